// Round 1
// baseline (299.311 us; speedup 1.0000x reference)
//
#include <hip/hip_runtime.h>
#include <hip/hip_bf16.h>
#include <math.h>

#define S_LEN 2048
#define DIN   1024
#define NH    16
#define NG    4

typedef short s16x8 __attribute__((ext_vector_type(8)));
typedef float f32x4 __attribute__((ext_vector_type(4)));

__device__ __forceinline__ unsigned short f2bf(float x) {
  union { float f; unsigned u; } v; v.f = x;
  unsigned r = v.u + 0x7FFFu + ((v.u >> 16) & 1u);
  return (unsigned short)(r >> 16);
}

// ---- Kernel 1: weights f32 [u][d][e] -> bf16 transposed [u][e][d] -------
// units: 0..15 = Wq heads, 16..19 = Wk groups, 20..23 = Wv groups
__global__ __launch_bounds__(256) void k_wtrans(
    const float* __restrict__ Wq, const float* __restrict__ Wk,
    const float* __restrict__ Wv, unsigned short* __restrict__ out) {
  int idx = blockIdx.x * 256 + threadIdx.x;   // 24*65536 total, exact grid
  int u = idx >> 16, r = idx & 65535, d = r >> 6, e = r & 63;
  const float* src = (u < 16) ? (Wq + (size_t)u * 65536)
                   : (u < 20) ? (Wk + (size_t)(u - 16) * 65536)
                              : (Wv + (size_t)(u - 20) * 65536);
  out[(size_t)u * 65536 + e * 1024 + d] = f2bf(src[d * 64 + e]);
}

// ---- Kernel 2: projections. grid (S/128, B*24), 256 thr = 4 waves ------
__global__ __launch_bounds__(256) void k_project(
    const float* __restrict__ query, const float* __restrict__ key,
    const float* __restrict__ value,
    const float* __restrict__ bq, const float* __restrict__ bk,
    const float* __restrict__ bv,
    const unsigned short* __restrict__ Wt,  // [24][64][1024] bf16
    unsigned short* __restrict__ Qb,        // [B][H][S][64] bf16
    unsigned short* __restrict__ Kb,        // [B][G][S][64] bf16
    unsigned short* __restrict__ Vt) {      // [B][G][64][S] bf16
  __shared__ __align__(16) unsigned short A[128][72];  // +8 pad: 2-way banks
  const int m0 = blockIdx.x * 128;
  const int b = blockIdx.y / 24, u = blockIdx.y % 24;
  const int tid = threadIdx.x;
  const int w = tid >> 6, lane = tid & 63, lq = lane & 15, gq = lane >> 4;

  const float* src; const float* bias;
  if (u < 16)      { src = query; bias = bq + u * 64; }
  else if (u < 20) { src = key;   bias = bk + (u - 16) * 64; }
  else             { src = value; bias = bv + (u - 20) * 64; }
  src += (size_t)b * S_LEN * DIN;
  const unsigned short* wt = Wt + (size_t)u * 65536;

  f32x4 acc[2][4] = {};

  for (int k0 = 0; k0 < DIN; k0 += 64) {
    // stage A tile (128 x 64) f32 -> bf16 into LDS, coalesced float4
    const int col = (tid & 15) * 4;
    const int rb  = tid >> 4;
    #pragma unroll
    for (int p = 0; p < 8; ++p) {
      const int row = p * 16 + rb;
      float4 v = *(const float4*)(src + (size_t)(m0 + row) * DIN + k0 + col);
      unsigned lo = (unsigned)f2bf(v.x) | ((unsigned)f2bf(v.y) << 16);
      unsigned hi = (unsigned)f2bf(v.z) | ((unsigned)f2bf(v.w) << 16);
      *(uint2*)&A[row][col] = make_uint2(lo, hi);
    }
    __syncthreads();
    #pragma unroll
    for (int kk = 0; kk < 2; ++kk) {
      s16x8 a0 = *(const s16x8*)&A[w * 32 + lq][kk * 32 + gq * 8];
      s16x8 a1 = *(const s16x8*)&A[w * 32 + 16 + lq][kk * 32 + gq * 8];
      #pragma unroll
      for (int n = 0; n < 4; ++n) {
        s16x8 bb = *(const s16x8*)(wt + (size_t)(n * 16 + lq) * 1024 +
                                   k0 + kk * 32 + gq * 8);
        acc[0][n] = __builtin_amdgcn_mfma_f32_16x16x32_bf16(a0, bb, acc[0][n], 0, 0, 0);
        acc[1][n] = __builtin_amdgcn_mfma_f32_16x16x32_bf16(a1, bb, acc[1][n], 0, 0, 0);
      }
    }
    __syncthreads();
  }

  float bvv[4];
  #pragma unroll
  for (int n = 0; n < 4; ++n) bvv[n] = bias[n * 16 + lq];

  if (u < 20) {  // Q or K: row-major [s][e]
    unsigned short* outp = (u < 16)
        ? Qb + (size_t)(b * NH + u) * S_LEN * 64
        : Kb + (size_t)(b * NG + (u - 16)) * S_LEN * 64;
    #pragma unroll
    for (int rg = 0; rg < 2; ++rg)
      #pragma unroll
      for (int n = 0; n < 4; ++n)
        #pragma unroll
        for (int r = 0; r < 4; ++r) {
          int s = m0 + w * 32 + rg * 16 + gq * 4 + r;
          outp[(size_t)s * 64 + n * 16 + lq] = f2bf(acc[rg][n][r] + bvv[n]);
        }
  } else {       // V: transposed [e][s] (scatter; lines filled within block)
    unsigned short* outp = Vt + (size_t)(b * NG + (u - 20)) * 64 * S_LEN;
    #pragma unroll
    for (int rg = 0; rg < 2; ++rg)
      #pragma unroll
      for (int n = 0; n < 4; ++n)
        #pragma unroll
        for (int r = 0; r < 4; ++r) {
          int s = m0 + w * 32 + rg * 16 + gq * 4 + r;
          outp[(size_t)(n * 16 + lq) * S_LEN + s] = f2bf(acc[rg][n][r] + bvv[n]);
        }
  }
}

// ---- Kernel 3: causal flash attention. grid (S/64, H, B), 4 waves ------
__global__ __launch_bounds__(256) void k_attn(
    const unsigned short* __restrict__ Qb, const unsigned short* __restrict__ Kb,
    const unsigned short* __restrict__ Vt, float* __restrict__ out) {
  __shared__ __align__(16) unsigned short P[4][16][56];  // wave-private P tiles
  const int q0 = blockIdx.x * 64;
  const int h = blockIdx.y, b = blockIdx.z, g = h & 3;
  const int tid = threadIdx.x;
  const int w = tid >> 6, lane = tid & 63, lq = lane & 15, gq = lane >> 4;
  const int qrow = q0 + w * 16 + lq;

  const unsigned short* Qp = Qb + ((size_t)(b * NH + h) * S_LEN + qrow) * 64;
  const unsigned short* Kp = Kb + (size_t)(b * NG + g) * S_LEN * 64;
  const unsigned short* Vp = Vt + (size_t)(b * NG + g) * 64 * S_LEN;

  // Q fragments held in registers for the whole KV loop
  s16x8 qf0 = *(const s16x8*)(Qp + gq * 8);
  s16x8 qf1 = *(const s16x8*)(Qp + 32 + gq * 8);

  f32x4 z[4] = {};
  float m = -INFINITY, l = 0.f;
  const float SC = 0.1803368801111204f;  // log2(e) / sqrt(DIM=64)

  const int ntiles = (q0 + 64) >> 5;     // causal bound, uniform per block
  for (int t = 0; t < ntiles; ++t) {
    const int k0 = t * 32;
    // S^T = K * Q^T : lane holds q = lane&15, k = k0 + f*16 + gq*4 + r
    float sv[2][4]; float pmax = -INFINITY;
    #pragma unroll
    for (int f = 0; f < 2; ++f) {
      const unsigned short* kp = Kp + (size_t)(k0 + f * 16 + lq) * 64 + gq * 8;
      s16x8 ka = *(const s16x8*)kp;
      s16x8 kb = *(const s16x8*)(kp + 32);
      f32x4 sa = {};
      sa = __builtin_amdgcn_mfma_f32_16x16x32_bf16(ka, qf0, sa, 0, 0, 0);
      sa = __builtin_amdgcn_mfma_f32_16x16x32_bf16(kb, qf1, sa, 0, 0, 0);
      #pragma unroll
      for (int r = 0; r < 4; ++r) {
        int kpos = k0 + f * 16 + gq * 4 + r;
        float x = sa[r] * SC;
        x = (kpos > qrow) ? -1e30f : x;   // causal mask
        sv[f][r] = x;
        pmax = fmaxf(pmax, x);
      }
    }
    // row reduce across the 4 lane-groups holding this q
    pmax = fmaxf(pmax, __shfl_xor(pmax, 16));
    pmax = fmaxf(pmax, __shfl_xor(pmax, 32));
    const float mn = fmaxf(m, pmax);
    const float sc = __builtin_amdgcn_exp2f(m - mn);  // m=-inf -> 0
    float ps = 0.f;
    unsigned pw[2][2];
    #pragma unroll
    for (int f = 0; f < 2; ++f) {
      float p0 = __builtin_amdgcn_exp2f(sv[f][0] - mn);
      float p1 = __builtin_amdgcn_exp2f(sv[f][1] - mn);
      float p2 = __builtin_amdgcn_exp2f(sv[f][2] - mn);
      float p3 = __builtin_amdgcn_exp2f(sv[f][3] - mn);
      ps += (p0 + p1) + (p2 + p3);
      pw[f][0] = (unsigned)f2bf(p0) | ((unsigned)f2bf(p1) << 16);
      pw[f][1] = (unsigned)f2bf(p2) | ((unsigned)f2bf(p3) << 16);
    }
    ps += __shfl_xor(ps, 16);
    ps += __shfl_xor(ps, 32);
    l = l * sc + ps; m = mn;
    // rescale z acc: z rows live at q = gq*4+r -> fetch that row's scale
    #pragma unroll
    for (int r = 0; r < 4; ++r) {
      float scr = __shfl(sc, gq * 4 + r, 64);
      z[0][r] *= scr; z[1][r] *= scr; z[2][r] *= scr; z[3][r] *= scr;
    }
    // P (bf16) -> LDS [q][k], then read back as PV A-fragment
    *(unsigned*)&P[w][lq][gq * 4]          = pw[0][0];
    *(unsigned*)&P[w][lq][gq * 4 + 2]      = pw[0][1];
    *(unsigned*)&P[w][lq][16 + gq * 4]     = pw[1][0];
    *(unsigned*)&P[w][lq][16 + gq * 4 + 2] = pw[1][1];
    __syncthreads();
    s16x8 pa = *(const s16x8*)&P[w][lq][gq * 8];
    #pragma unroll
    for (int n = 0; n < 4; ++n) {
      s16x8 vb = *(const s16x8*)(Vp + (size_t)(n * 16 + lq) * S_LEN + k0 + gq * 8);
      z[n] = __builtin_amdgcn_mfma_f32_16x16x32_bf16(pa, vb, z[n], 0, 0, 0);
    }
    __syncthreads();
  }

  // epilogue: divide by l and store f32
  #pragma unroll
  for (int r = 0; r < 4; ++r) {
    float lr = __shfl(l, gq * 4 + r, 64);
    float inv = __builtin_amdgcn_rcpf(lr);
    const int s = q0 + w * 16 + gq * 4 + r;
    float* op = out + ((size_t)b * S_LEN + s) * 1024 + h * 64;
    #pragma unroll
    for (int n = 0; n < 4; ++n) op[n * 16 + lq] = z[n][r] * inv;
  }
}

extern "C" void kernel_launch(void* const* d_in, const int* in_sizes, int n_in,
                              void* d_out, int out_size, void* d_ws, size_t ws_size,
                              hipStream_t stream) {
  const float* query = (const float*)d_in[0];
  const float* key   = (const float*)d_in[1];
  const float* value = (const float*)d_in[2];
  // d_in[3] = mask (causal tril; applied analytically)
  const float* Wq = (const float*)d_in[4];
  const float* bq = (const float*)d_in[5];
  const float* Wk = (const float*)d_in[6];
  const float* bk = (const float*)d_in[7];
  const float* Wv = (const float*)d_in[8];
  const float* bv = (const float*)d_in[9];
  float* out = (float*)d_out;

  unsigned short* Qb = (unsigned short*)d_ws;                 // 4,194,304
  unsigned short* Kb = Qb + (size_t)2 * NH * S_LEN * 64;      // 1,048,576
  unsigned short* Vt = Kb + (size_t)2 * NG * S_LEN * 64;      // 1,048,576
  unsigned short* Wt = Vt + (size_t)2 * NG * S_LEN * 64;      // 1,572,864
  // total ws use: 15.7 MB

  hipLaunchKernelGGL(k_wtrans, dim3(6144), dim3(256), 0, stream, Wq, Wk, Wv, Wt);
  hipLaunchKernelGGL(k_project, dim3(16, 48), dim3(256), 0, stream,
                     query, key, value, bq, bk, bv, Wt, Qb, Kb, Vt);
  hipLaunchKernelGGL(k_attn, dim3(32, NH, 2), dim3(256), 0, stream, Qb, Kb, Vt, out);
}

// Round 2
// 227.325 us; speedup vs baseline: 1.3167x; 1.3167x over previous
//
#include <hip/hip_runtime.h>
#include <hip/hip_bf16.h>
#include <math.h>

#define S_LEN 2048
#define DIN   1024
#define NH    16
#define NG    4

typedef short s16x8 __attribute__((ext_vector_type(8)));
typedef float f32x4 __attribute__((ext_vector_type(4)));

__device__ __forceinline__ unsigned short f2bf(float x) {
  union { float f; unsigned u; } v; v.f = x;
  unsigned r = v.u + 0x7FFFu + ((v.u >> 16) & 1u);
  return (unsigned short)(r >> 16);
}

// pack 8 f32 -> 8 bf16 (RNE) via v_cvt_pk_bf16_f32
__device__ __forceinline__ s16x8 cvt8(float4 a, float4 b) {
  union { s16x8 v; unsigned u[4]; } r;
  asm("v_cvt_pk_bf16_f32 %0, %1, %2" : "=v"(r.u[0]) : "v"(a.x), "v"(a.y));
  asm("v_cvt_pk_bf16_f32 %0, %1, %2" : "=v"(r.u[1]) : "v"(a.z), "v"(a.w));
  asm("v_cvt_pk_bf16_f32 %0, %1, %2" : "=v"(r.u[2]) : "v"(b.x), "v"(b.y));
  asm("v_cvt_pk_bf16_f32 %0, %1, %2" : "=v"(r.u[3]) : "v"(b.z), "v"(b.w));
  return r.v;
}

// ---- Kernel 1: weights f32 [u][d][e] -> bf16 transposed [u][e][d] -------
__global__ __launch_bounds__(256) void k_wtrans(
    const float* __restrict__ Wq, const float* __restrict__ Wk,
    const float* __restrict__ Wv, unsigned short* __restrict__ out) {
  int idx = blockIdx.x * 256 + threadIdx.x;   // 24*65536 total, exact grid
  int u = idx >> 16, r = idx & 65535, d = r >> 6, e = r & 63;
  const float* src = (u < 16) ? (Wq + (size_t)u * 65536)
                   : (u < 20) ? (Wk + (size_t)(u - 16) * 65536)
                              : (Wv + (size_t)(u - 20) * 65536);
  out[(size_t)u * 65536 + e * 1024 + d] = f2bf(src[d * 64 + e]);
}

// ---- Kernel 2: projections. grid 768 (XCD-chunked), 4 waves ------------
// block -> (strip of 128 rows, batch, unit); direct f32 A-frag loads + cvt
__global__ __launch_bounds__(256) void k_project(
    const float* __restrict__ query, const float* __restrict__ key,
    const float* __restrict__ value,
    const float* __restrict__ bq, const float* __restrict__ bk,
    const float* __restrict__ bv,
    const unsigned short* __restrict__ Wt,  // [24][64][1024] bf16
    unsigned short* __restrict__ Qb,        // [B][H][S][64] bf16
    unsigned short* __restrict__ Kb,        // [B][G][S][64] bf16
    unsigned short* __restrict__ Vt) {      // [B][G][64][S] bf16
  const int i   = blockIdx.x;                 // 768 blocks
  const int lid = (i & 7) * 96 + (i >> 3);    // chunk per XCD: strip locality
  const int strip = lid / 48;
  const int rr  = lid % 48;
  const int b = rr / 24, u = rr % 24;
  const int tid = threadIdx.x;
  const int w = tid >> 6, lane = tid & 63, lq = lane & 15, gq = lane >> 4;
  const int row0 = strip * 128 + w * 32;

  const float* src; const float* bias;
  if (u < 16)      { src = query; bias = bq + u * 64; }
  else if (u < 20) { src = key;   bias = bk + (u - 16) * 64; }
  else             { src = value; bias = bv + (u - 20) * 64; }
  src += (size_t)b * S_LEN * DIN;
  const unsigned short* wt = Wt + (size_t)u * 65536;

  f32x4 acc[2][4] = {};

  for (int k0 = 0; k0 < DIN; k0 += 32) {
    s16x8 a[2];
    #pragma unroll
    for (int rf = 0; rf < 2; ++rf) {
      const float* ap = src + (size_t)(row0 + rf * 16 + lq) * DIN + k0 + gq * 8;
      float4 x = *(const float4*)ap;
      float4 y = *(const float4*)(ap + 4);
      a[rf] = cvt8(x, y);
    }
    #pragma unroll
    for (int n = 0; n < 4; ++n) {
      s16x8 bb = *(const s16x8*)(wt + (size_t)(n * 16 + lq) * 1024 + k0 + gq * 8);
      acc[0][n] = __builtin_amdgcn_mfma_f32_16x16x32_bf16(a[0], bb, acc[0][n], 0, 0, 0);
      acc[1][n] = __builtin_amdgcn_mfma_f32_16x16x32_bf16(a[1], bb, acc[1][n], 0, 0, 0);
    }
  }

  float bvv[4];
  #pragma unroll
  for (int n = 0; n < 4; ++n) bvv[n] = bias[n * 16 + lq];

  if (u < 20) {  // Q or K: row-major [s][e]
    unsigned short* outp = (u < 16)
        ? Qb + (size_t)(b * NH + u) * S_LEN * 64
        : Kb + (size_t)(b * NG + (u - 16)) * S_LEN * 64;
    #pragma unroll
    for (int rg = 0; rg < 2; ++rg)
      #pragma unroll
      for (int n = 0; n < 4; ++n)
        #pragma unroll
        for (int r = 0; r < 4; ++r) {
          int s = row0 + rg * 16 + gq * 4 + r;
          outp[(size_t)s * 64 + n * 16 + lq] = f2bf(acc[rg][n][r] + bvv[n]);
        }
  } else {       // V: transposed [e][s]
    unsigned short* outp = Vt + (size_t)(b * NG + (u - 20)) * 64 * S_LEN;
    #pragma unroll
    for (int rg = 0; rg < 2; ++rg)
      #pragma unroll
      for (int n = 0; n < 4; ++n)
        #pragma unroll
        for (int r = 0; r < 4; ++r) {
          int s = row0 + rg * 16 + gq * 4 + r;
          outp[(size_t)(n * 16 + lq) * S_LEN + s] = f2bf(acc[rg][n][r] + bvv[n]);
        }
  }
}

// ---- Kernel 3: causal flash attention. grid (16,H,B), 4 indep waves ----
// wave = 32 q-rows, KBLK=64, no block barriers (P is wave-private)
__global__ __launch_bounds__(256) void k_attn(
    const unsigned short* __restrict__ Qb, const unsigned short* __restrict__ Kb,
    const unsigned short* __restrict__ Vt, float* __restrict__ out) {
  __shared__ __align__(16) unsigned short P[4][32][72];  // wave-private
  const int tid = threadIdx.x;
  const int w = tid >> 6, lane = tid & 63, lq = lane & 15, gq = lane >> 4;
  const int strip = (15 - blockIdx.x) * 4 + w;   // heavy strips dispatch first
  const int qs = strip * 32;
  const int h = blockIdx.y, b = blockIdx.z, g = h & 3;

  const unsigned short* Qp = Qb + ((size_t)(b * NH + h) * S_LEN + qs) * 64;
  const unsigned short* Kp = Kb + (size_t)(b * NG + g) * S_LEN * 64;
  const unsigned short* Vp = Vt + (size_t)(b * NG + g) * 64 * S_LEN;

  // Q B-fragments (col = q = lane&15), held for the whole KV loop
  s16x8 qf[2][2];
  #pragma unroll
  for (int qh = 0; qh < 2; ++qh)
    #pragma unroll
    for (int dk = 0; dk < 2; ++dk)
      qf[qh][dk] = *(const s16x8*)(Qp + (size_t)(qh * 16 + lq) * 64 + dk * 32 + gq * 8);

  f32x4 z[2][4] = {};
  float m[2] = {-INFINITY, -INFINITY}, l[2] = {0.f, 0.f};
  const float SC = 0.1803368801111204f;  // log2(e)/sqrt(64)

  const int ntiles = (qs >> 6) + 1;
  for (int t = 0; t < ntiles; ++t) {
    const int k0 = t * 64;
    const bool lastt = (t == ntiles - 1);
    // S^T = K * Q^T : lane holds q = qh*16 + lq ; k = k0 + f*16 + gq*4 + r
    f32x4 sv[2][4];
    #pragma unroll
    for (int f = 0; f < 4; ++f) {
      const unsigned short* kp = Kp + (size_t)(k0 + f * 16 + lq) * 64 + gq * 8;
      s16x8 ka = *(const s16x8*)kp;
      s16x8 kb = *(const s16x8*)(kp + 32);
      #pragma unroll
      for (int qh = 0; qh < 2; ++qh) {
        f32x4 s = {};
        s = __builtin_amdgcn_mfma_f32_16x16x32_bf16(ka, qf[qh][0], s, 0, 0, 0);
        s = __builtin_amdgcn_mfma_f32_16x16x32_bf16(kb, qf[qh][1], s, 0, 0, 0);
        sv[qh][f] = s;
      }
    }
    float pmax[2] = {-INFINITY, -INFINITY};
    #pragma unroll
    for (int qh = 0; qh < 2; ++qh)
      #pragma unroll
      for (int f = 0; f < 4; ++f)
        #pragma unroll
        for (int r = 0; r < 4; ++r) {
          float x = sv[qh][f][r] * SC;
          if (lastt) {
            int kpos = k0 + f * 16 + gq * 4 + r;
            int qrow = qs + qh * 16 + lq;
            x = (kpos > qrow) ? -1e30f : x;
          }
          sv[qh][f][r] = x;
          pmax[qh] = fmaxf(pmax[qh], x);
        }
    #pragma unroll
    for (int qh = 0; qh < 2; ++qh) {
      pmax[qh] = fmaxf(pmax[qh], __shfl_xor(pmax[qh], 16));
      pmax[qh] = fmaxf(pmax[qh], __shfl_xor(pmax[qh], 32));
    }
    float sc[2], ps[2];
    #pragma unroll
    for (int qh = 0; qh < 2; ++qh) {
      const float mn = fmaxf(m[qh], pmax[qh]);
      sc[qh] = __builtin_amdgcn_exp2f(m[qh] - mn);
      m[qh] = mn;
      float s0 = 0.f;
      #pragma unroll
      for (int f = 0; f < 4; ++f) {
        float p0 = __builtin_amdgcn_exp2f(sv[qh][f][0] - mn);
        float p1 = __builtin_amdgcn_exp2f(sv[qh][f][1] - mn);
        float p2 = __builtin_amdgcn_exp2f(sv[qh][f][2] - mn);
        float p3 = __builtin_amdgcn_exp2f(sv[qh][f][3] - mn);
        s0 += (p0 + p1) + (p2 + p3);
        unsigned w0 = (unsigned)f2bf(p0) | ((unsigned)f2bf(p1) << 16);
        unsigned w1 = (unsigned)f2bf(p2) | ((unsigned)f2bf(p3) << 16);
        *(unsigned*)&P[w][qh * 16 + lq][f * 16 + gq * 4]     = w0;
        *(unsigned*)&P[w][qh * 16 + lq][f * 16 + gq * 4 + 2] = w1;
      }
      s0 += __shfl_xor(s0, 16);
      s0 += __shfl_xor(s0, 32);
      ps[qh] = s0;
      l[qh] = l[qh] * sc[qh] + s0;
    }
    // rescale accumulators (z row q = qh*16 + gq*4 + r)
    #pragma unroll
    for (int qh = 0; qh < 2; ++qh)
      #pragma unroll
      for (int r = 0; r < 4; ++r) {
        float scr = __shfl(sc[qh], gq * 4 + r, 64);
        z[qh][0][r] *= scr; z[qh][1][r] *= scr;
        z[qh][2][r] *= scr; z[qh][3][r] *= scr;
      }
    // PV: A = P[q][k] from LDS (same wave; compiler orders via lgkmcnt)
    s16x8 pa[2][2];
    #pragma unroll
    for (int qh = 0; qh < 2; ++qh)
      #pragma unroll
      for (int ks = 0; ks < 2; ++ks)
        pa[qh][ks] = *(const s16x8*)&P[w][qh * 16 + lq][ks * 32 + gq * 8];
    #pragma unroll
    for (int n = 0; n < 4; ++n)
      #pragma unroll
      for (int ks = 0; ks < 2; ++ks) {
        s16x8 vb = *(const s16x8*)(Vp + (size_t)(n * 16 + lq) * S_LEN + k0 + ks * 32 + gq * 8);
        z[0][n] = __builtin_amdgcn_mfma_f32_16x16x32_bf16(pa[0][ks], vb, z[0][n], 0, 0, 0);
        z[1][n] = __builtin_amdgcn_mfma_f32_16x16x32_bf16(pa[1][ks], vb, z[1][n], 0, 0, 0);
      }
  }

  // epilogue: divide by l, store f32
  #pragma unroll
  for (int qh = 0; qh < 2; ++qh)
    #pragma unroll
    for (int r = 0; r < 4; ++r) {
      float lr = __shfl(l[qh], gq * 4 + r, 64);
      float inv = __builtin_amdgcn_rcpf(lr);
      const int s = qs + qh * 16 + gq * 4 + r;
      float* op = out + ((size_t)b * S_LEN + s) * 1024 + h * 64;
      #pragma unroll
      for (int n = 0; n < 4; ++n) op[n * 16 + lq] = z[qh][n][r] * inv;
    }
}

extern "C" void kernel_launch(void* const* d_in, const int* in_sizes, int n_in,
                              void* d_out, int out_size, void* d_ws, size_t ws_size,
                              hipStream_t stream) {
  const float* query = (const float*)d_in[0];
  const float* key   = (const float*)d_in[1];
  const float* value = (const float*)d_in[2];
  // d_in[3] = mask (causal tril; applied analytically)
  const float* Wq = (const float*)d_in[4];
  const float* bq = (const float*)d_in[5];
  const float* Wk = (const float*)d_in[6];
  const float* bk = (const float*)d_in[7];
  const float* Wv = (const float*)d_in[8];
  const float* bv = (const float*)d_in[9];
  float* out = (float*)d_out;

  unsigned short* Qb = (unsigned short*)d_ws;                 // 4,194,304
  unsigned short* Kb = Qb + (size_t)2 * NH * S_LEN * 64;      // 1,048,576
  unsigned short* Vt = Kb + (size_t)2 * NG * S_LEN * 64;      // 1,048,576
  unsigned short* Wt = Vt + (size_t)2 * NG * S_LEN * 64;      // 1,572,864
  // total ws use: 15.7 MB

  hipLaunchKernelGGL(k_wtrans, dim3(6144), dim3(256), 0, stream, Wq, Wk, Wv, Wt);
  hipLaunchKernelGGL(k_project, dim3(768), dim3(256), 0, stream,
                     query, key, value, bq, bk, bv, Wt, Qb, Kb, Vt);
  hipLaunchKernelGGL(k_attn, dim3(16, NH, 2), dim3(256), 0, stream, Qb, Kb, Vt, out);
}

// Round 3
// 213.454 us; speedup vs baseline: 1.4022x; 1.0650x over previous
//
#include <hip/hip_runtime.h>
#include <hip/hip_bf16.h>
#include <math.h>

#define S_LEN 2048
#define DIN   1024
#define NH    16
#define NG    4

typedef short s16x8 __attribute__((ext_vector_type(8)));
typedef float f32x4 __attribute__((ext_vector_type(4)));

__device__ __forceinline__ unsigned short f2bf(float x) {
  union { float f; unsigned u; } v; v.f = x;
  unsigned r = v.u + 0x7FFFu + ((v.u >> 16) & 1u);
  return (unsigned short)(r >> 16);
}

__device__ __forceinline__ unsigned cvtpk(float a, float b) {
  unsigned r;
  asm("v_cvt_pk_bf16_f32 %0, %1, %2" : "=v"(r) : "v"(a), "v"(b));
  return r;
}

// pack 8 f32 -> 8 bf16 (RNE) via v_cvt_pk_bf16_f32
__device__ __forceinline__ s16x8 cvt8(float4 a, float4 b) {
  union { s16x8 v; unsigned u[4]; } r;
  r.u[0] = cvtpk(a.x, a.y); r.u[1] = cvtpk(a.z, a.w);
  r.u[2] = cvtpk(b.x, b.y); r.u[3] = cvtpk(b.z, b.w);
  return r.v;
}

// ---- Kernel 1: weights f32 [u][d][e] -> bf16 [u][e][d], LDS transpose ---
// grid 24*16; block handles one (u, 64-row d-block); coalesced in and out
__global__ __launch_bounds__(256) void k_wtrans(
    const float* __restrict__ Wq, const float* __restrict__ Wk,
    const float* __restrict__ Wv, unsigned short* __restrict__ out) {
  __shared__ __align__(16) unsigned short T[64][72];
  const int u = blockIdx.x >> 4, db = blockIdx.x & 15, D0 = db * 64;
  const int t = threadIdx.x;
  const float* src = (u < 16) ? (Wq + (size_t)u * 65536)
                   : (u < 20) ? (Wk + (size_t)(u - 16) * 65536)
                              : (Wv + (size_t)(u - 20) * 65536);
  const int e4 = (t & 15) * 4, dl = t >> 4;
  #pragma unroll
  for (int p = 0; p < 4; ++p) {
    const int d = p * 16 + dl;
    float4 v = *(const float4*)(src + (size_t)(D0 + d) * 64 + e4);
    T[e4 + 0][d] = f2bf(v.x); T[e4 + 1][d] = f2bf(v.y);
    T[e4 + 2][d] = f2bf(v.z); T[e4 + 3][d] = f2bf(v.w);
  }
  __syncthreads();
  const int j = t & 7;
  #pragma unroll
  for (int p = 0; p < 2; ++p) {
    const int e = p * 32 + (t >> 3);
    *(s16x8*)(out + (size_t)u * 65536 + e * 1024 + D0 + j * 8) =
        *(const s16x8*)&T[e][j * 8];
  }
}

// ---- Kernel 2: projections. grid 768 (XCD-chunked), 4 waves ------------
__global__ __launch_bounds__(256) void k_project(
    const float* __restrict__ query, const float* __restrict__ key,
    const float* __restrict__ value,
    const float* __restrict__ bq, const float* __restrict__ bk,
    const float* __restrict__ bv,
    const unsigned short* __restrict__ Wt,  // [24][64][1024] bf16
    unsigned short* __restrict__ Qb,        // [B][H][S][64] bf16
    unsigned short* __restrict__ Kb,        // [B][G][S][64] bf16
    unsigned short* __restrict__ Vt) {      // [B][G][64][S] bf16
  const int i   = blockIdx.x;                 // 768 blocks
  const int lid = (i & 7) * 96 + (i >> 3);    // chunk per XCD: strip locality
  const int strip = lid / 48;
  const int rr  = lid % 48;
  const int b = rr / 24, u = rr % 24;
  const int tid = threadIdx.x;
  const int w = tid >> 6, lane = tid & 63, lq = lane & 15, gq = lane >> 4;
  const int row0 = strip * 128 + w * 32;

  const float* src; const float* bias;
  if (u < 16)      { src = query; bias = bq + u * 64; }
  else if (u < 20) { src = key;   bias = bk + (u - 16) * 64; }
  else             { src = value; bias = bv + (u - 20) * 64; }
  src += (size_t)b * S_LEN * DIN;
  const unsigned short* wt = Wt + (size_t)u * 65536;

  f32x4 acc[2][4] = {};

  for (int k0 = 0; k0 < DIN; k0 += 32) {
    s16x8 a[2];
    #pragma unroll
    for (int rf = 0; rf < 2; ++rf) {
      const float* ap = src + (size_t)(row0 + rf * 16 + lq) * DIN + k0 + gq * 8;
      float4 x = *(const float4*)ap;
      float4 y = *(const float4*)(ap + 4);
      a[rf] = cvt8(x, y);
    }
    #pragma unroll
    for (int n = 0; n < 4; ++n) {
      s16x8 bb = *(const s16x8*)(wt + (size_t)(n * 16 + lq) * 1024 + k0 + gq * 8);
      acc[0][n] = __builtin_amdgcn_mfma_f32_16x16x32_bf16(a[0], bb, acc[0][n], 0, 0, 0);
      acc[1][n] = __builtin_amdgcn_mfma_f32_16x16x32_bf16(a[1], bb, acc[1][n], 0, 0, 0);
    }
  }

  float bvv[4];
  #pragma unroll
  for (int n = 0; n < 4; ++n) bvv[n] = bias[n * 16 + lq];

  if (u < 20) {  // Q or K: row-major [s][e]
    unsigned short* outp = (u < 16)
        ? Qb + (size_t)(b * NH + u) * S_LEN * 64
        : Kb + (size_t)(b * NG + (u - 16)) * S_LEN * 64;
    #pragma unroll
    for (int rg = 0; rg < 2; ++rg)
      #pragma unroll
      for (int n = 0; n < 4; ++n)
        #pragma unroll
        for (int r = 0; r < 4; ++r) {
          int s = row0 + rg * 16 + gq * 4 + r;
          outp[(size_t)s * 64 + n * 16 + lq] = f2bf(acc[rg][n][r] + bvv[n]);
        }
  } else {       // V: transposed [e][s]
    unsigned short* outp = Vt + (size_t)(b * NG + (u - 20)) * 64 * S_LEN;
    #pragma unroll
    for (int rg = 0; rg < 2; ++rg)
      #pragma unroll
      for (int n = 0; n < 4; ++n)
        #pragma unroll
        for (int r = 0; r < 4; ++r) {
          int s = row0 + rg * 16 + gq * 4 + r;
          outp[(size_t)(n * 16 + lq) * S_LEN + s] = f2bf(acc[rg][n][r] + bvv[n]);
        }
  }
}

// ---- Kernel 3: causal flash attention. 1 wave/block, grid (64,H,B) -----
// wave = 32 q-rows, KBLK=64, K double-buffered, defer-max online softmax
__global__ __launch_bounds__(64) void k_attn(
    const unsigned short* __restrict__ Qb, const unsigned short* __restrict__ Kb,
    const unsigned short* __restrict__ Vt, float* __restrict__ out) {
  __shared__ __align__(16) unsigned short P[32][72];
  const int lane = threadIdx.x, lq = lane & 15, gq = lane >> 4;
  const int strip = 63 - blockIdx.x;        // heavy strips dispatch first
  const int qs = strip * 32;
  const int h = blockIdx.y, b = blockIdx.z, g = h & 3;

  const unsigned short* Qp = Qb + ((size_t)(b * NH + h) * S_LEN + qs) * 64;
  const unsigned short* Kp = Kb + (size_t)(b * NG + g) * S_LEN * 64;
  const unsigned short* Vp = Vt + (size_t)(b * NG + g) * 64 * S_LEN;

  // Q B-fragments (col = q = lane&15), held for the whole KV loop
  s16x8 qf[2][2];
  #pragma unroll
  for (int qh = 0; qh < 2; ++qh)
    #pragma unroll
    for (int dk = 0; dk < 2; ++dk)
      qf[qh][dk] = *(const s16x8*)(Qp + (size_t)(qh * 16 + lq) * 64 + dk * 32 + gq * 8);

  f32x4 z[2][4] = {};
  float m[2] = {-INFINITY, -INFINITY}, l[2] = {0.f, 0.f};
  const float SC = 0.1803368801111204f;  // log2(e)/sqrt(64)
  const int ntiles = (qs >> 6) + 1;

  auto loadK = [&](s16x8 (&A)[4], s16x8 (&B)[4], int k0) {
    #pragma unroll
    for (int f = 0; f < 4; ++f) {
      const unsigned short* kp = Kp + (size_t)(k0 + f * 16 + lq) * 64 + gq * 8;
      A[f] = *(const s16x8*)kp;
      B[f] = *(const s16x8*)(kp + 32);
    }
  };

  auto tile = [&](const s16x8 (&kA)[4], const s16x8 (&kB)[4], int t) {
    const int k0 = t * 64;
    const bool lastt = (t == ntiles - 1);
    // V fragment loads issued first: hidden under QK + softmax
    s16x8 vb[4][2];
    #pragma unroll
    for (int n = 0; n < 4; ++n)
      #pragma unroll
      for (int ks = 0; ks < 2; ++ks)
        vb[n][ks] = *(const s16x8*)(Vp + (size_t)(n * 16 + lq) * S_LEN +
                                    k0 + ks * 32 + gq * 8);
    // S^T = K·Q^T : lane holds q = qh*16+lq ; k = k0 + f*16 + gq*4 + r
    f32x4 sv[2][4];
    #pragma unroll
    for (int f = 0; f < 4; ++f) {
      #pragma unroll
      for (int qh = 0; qh < 2; ++qh) {
        f32x4 s = {};
        s = __builtin_amdgcn_mfma_f32_16x16x32_bf16(kA[f], qf[qh][0], s, 0, 0, 0);
        s = __builtin_amdgcn_mfma_f32_16x16x32_bf16(kB[f], qf[qh][1], s, 0, 0, 0);
        sv[qh][f] = s;
      }
    }
    #pragma unroll
    for (int qh = 0; qh < 2; ++qh)
      #pragma unroll
      for (int f = 0; f < 4; ++f)
        #pragma unroll
        for (int r = 0; r < 4; ++r) sv[qh][f][r] *= SC;
    if (lastt) {
      #pragma unroll
      for (int qh = 0; qh < 2; ++qh)
        #pragma unroll
        for (int f = 0; f < 4; ++f)
          #pragma unroll
          for (int r = 0; r < 4; ++r) {
            int kpos = k0 + f * 16 + gq * 4 + r;
            int qrow = qs + qh * 16 + lq;
            if (kpos > qrow) sv[qh][f][r] = -1e30f;
          }
    }
    // tree max per q-row, then cross-group reduce
    float pmax[2];
    #pragma unroll
    for (int qh = 0; qh < 2; ++qh) {
      float mf[4];
      #pragma unroll
      for (int f = 0; f < 4; ++f)
        mf[f] = fmaxf(fmaxf(sv[qh][f][0], sv[qh][f][1]),
                      fmaxf(sv[qh][f][2], sv[qh][f][3]));
      float pm = fmaxf(fmaxf(mf[0], mf[1]), fmaxf(mf[2], mf[3]));
      pm = fmaxf(pm, __shfl_xor(pm, 16));
      pm = fmaxf(pm, __shfl_xor(pm, 32));
      pmax[qh] = pm;
    }
    // defer-max: rescale only when max grew by > 8 (P bounded by 2^8)
    const float grow = fmaxf(pmax[0] - m[0], pmax[1] - m[1]);
    if (__any(grow > 8.f)) {
      #pragma unroll
      for (int qh = 0; qh < 2; ++qh) {
        const float mn = fmaxf(m[qh], pmax[qh]);
        const float sc = __builtin_amdgcn_exp2f(m[qh] - mn);
        m[qh] = mn;
        l[qh] *= sc;
        #pragma unroll
        for (int r = 0; r < 4; ++r) {
          float scr = __shfl(sc, gq * 4 + r, 64);
          z[qh][0][r] *= scr; z[qh][1][r] *= scr;
          z[qh][2][r] *= scr; z[qh][3][r] *= scr;
        }
      }
    }
    // P = exp2(S - m), pack bf16, wave-private LDS layout swap
    #pragma unroll
    for (int qh = 0; qh < 2; ++qh) {
      const float mm = m[qh];
      float s0 = 0.f, s1 = 0.f;
      #pragma unroll
      for (int f = 0; f < 4; ++f) {
        float p0 = __builtin_amdgcn_exp2f(sv[qh][f][0] - mm);
        float p1 = __builtin_amdgcn_exp2f(sv[qh][f][1] - mm);
        float p2 = __builtin_amdgcn_exp2f(sv[qh][f][2] - mm);
        float p3 = __builtin_amdgcn_exp2f(sv[qh][f][3] - mm);
        s0 += p0 + p1; s1 += p2 + p3;
        uint2 wds = make_uint2(cvtpk(p0, p1), cvtpk(p2, p3));
        *(uint2*)&P[qh * 16 + lq][f * 16 + gq * 4] = wds;
      }
      float s = s0 + s1;
      s += __shfl_xor(s, 16);
      s += __shfl_xor(s, 32);
      l[qh] += s;
    }
    // PV: A = P[q][k] from LDS (same wave; lgkmcnt ordering)
    s16x8 pa[2][2];
    #pragma unroll
    for (int qh = 0; qh < 2; ++qh)
      #pragma unroll
      for (int ks = 0; ks < 2; ++ks)
        pa[qh][ks] = *(const s16x8*)&P[qh * 16 + lq][ks * 32 + gq * 8];
    #pragma unroll
    for (int n = 0; n < 4; ++n)
      #pragma unroll
      for (int ks = 0; ks < 2; ++ks) {
        z[0][n] = __builtin_amdgcn_mfma_f32_16x16x32_bf16(pa[0][ks], vb[n][ks], z[0][n], 0, 0, 0);
        z[1][n] = __builtin_amdgcn_mfma_f32_16x16x32_bf16(pa[1][ks], vb[n][ks], z[1][n], 0, 0, 0);
      }
  };

  // K double-buffer: manual 2x rotation, no register moves
  s16x8 cA[4], cB[4], nA[4], nB[4];
  loadK(cA, cB, 0);
  int t = 0;
  while (true) {
    int kn = (t + 1 < ntiles) ? (t + 1) * 64 : t * 64;
    loadK(nA, nB, kn);
    tile(cA, cB, t);
    if (++t >= ntiles) break;
    kn = (t + 1 < ntiles) ? (t + 1) * 64 : t * 64;
    loadK(cA, cB, kn);
    tile(nA, nB, t);
    if (++t >= ntiles) break;
  }

  // epilogue: divide by l, store f32
  #pragma unroll
  for (int qh = 0; qh < 2; ++qh)
    #pragma unroll
    for (int r = 0; r < 4; ++r) {
      float lr = __shfl(l[qh], gq * 4 + r, 64);
      float inv = __builtin_amdgcn_rcpf(lr);
      const int s = qs + qh * 16 + gq * 4 + r;
      float* op = out + ((size_t)b * S_LEN + s) * 1024 + h * 64;
      #pragma unroll
      for (int n = 0; n < 4; ++n) op[n * 16 + lq] = z[qh][n][r] * inv;
    }
}

extern "C" void kernel_launch(void* const* d_in, const int* in_sizes, int n_in,
                              void* d_out, int out_size, void* d_ws, size_t ws_size,
                              hipStream_t stream) {
  const float* query = (const float*)d_in[0];
  const float* key   = (const float*)d_in[1];
  const float* value = (const float*)d_in[2];
  // d_in[3] = mask (causal tril; applied analytically)
  const float* Wq = (const float*)d_in[4];
  const float* bq = (const float*)d_in[5];
  const float* Wk = (const float*)d_in[6];
  const float* bk = (const float*)d_in[7];
  const float* Wv = (const float*)d_in[8];
  const float* bv = (const float*)d_in[9];
  float* out = (float*)d_out;

  unsigned short* Qb = (unsigned short*)d_ws;                 // 4,194,304
  unsigned short* Kb = Qb + (size_t)2 * NH * S_LEN * 64;      // 1,048,576
  unsigned short* Vt = Kb + (size_t)2 * NG * S_LEN * 64;      // 1,048,576
  unsigned short* Wt = Vt + (size_t)2 * NG * S_LEN * 64;      // 1,572,864

  hipLaunchKernelGGL(k_wtrans, dim3(384), dim3(256), 0, stream, Wq, Wk, Wv, Wt);
  hipLaunchKernelGGL(k_project, dim3(768), dim3(256), 0, stream,
                     query, key, value, bq, bk, bv, Wt, Qb, Kb, Vt);
  hipLaunchKernelGGL(k_attn, dim3(64, NH, 2), dim3(64), 0, stream, Qb, Kb, Vt, out);
}

// Round 6
// 100.765 us; speedup vs baseline: 2.9704x; 2.1183x over previous
//
#include <hip/hip_runtime.h>
#include <hip/hip_bf16.h>
#include <math.h>

#define S_LEN 2048
#define DIN   1024
#define NH    16
#define NG    4

typedef short s16x8 __attribute__((ext_vector_type(8)));
typedef float f32x4 __attribute__((ext_vector_type(4)));

__device__ __forceinline__ unsigned short f2bf(float x) {
  union { float f; unsigned u; } v; v.f = x;
  unsigned r = v.u + 0x7FFFu + ((v.u >> 16) & 1u);
  return (unsigned short)(r >> 16);
}
__device__ __forceinline__ unsigned cvtpk(float a, float b) {
  unsigned r;
  asm("v_cvt_pk_bf16_f32 %0, %1, %2" : "=v"(r) : "v"(a), "v"(b));
  return r;
}

// Fragment-major tile: 16(rows) x 32(k), 512 elems = 1KB bf16, stored
// LANE-MAJOR: offset = row*8 + ((k>>3)&3)*128 + (k&7), so that lane
// l = row + 16*(k>>3) reads its 8 contiguous elements at base + l*8.

// ---- k_cast: q/k/v f32 [b][s][d] -> AF bf16 fragment-major ------------
// AF per input: [b:2][s>>4:128][d>>5:32][512]; thread = 8 d-elems
__global__ __launch_bounds__(256) void k_cast(
    const float* __restrict__ q, const float* __restrict__ k,
    const float* __restrict__ v, unsigned short* __restrict__ AF) {
  const float* src = (blockIdx.y == 0) ? q : (blockIdx.y == 1) ? k : v;
  unsigned short* dst = AF + (size_t)blockIdx.y * 4194304;
  int flat = blockIdx.x * 256 + threadIdx.x;            // [0, 524288)
  int b = flat >> 18, s = (flat >> 7) & 2047, d0 = (flat & 127) * 8;
  const float* sp = src + (size_t)(b * 2048 + s) * 1024 + d0;
  float4 x = *(const float4*)sp;
  float4 y = *(const float4*)(sp + 4);
  union { s16x8 v; unsigned u[4]; } r;
  r.u[0] = cvtpk(x.x, x.y); r.u[1] = cvtpk(x.z, x.w);
  r.u[2] = cvtpk(y.x, y.y); r.u[3] = cvtpk(y.z, y.w);
  unsigned short* p = dst + (size_t)((b * 128 + (s >> 4)) * 32 + (d0 >> 5)) * 512
                    + (s & 15) * 8 + ((d0 >> 3) & 3) * 128;
  *(s16x8*)p = r.v;
}

// ---- k_wtrans: W f32 [u][d][e] -> WF bf16 frag-major [u][e>>4][d>>5][512]
__global__ __launch_bounds__(256) void k_wtrans(
    const float* __restrict__ Wq, const float* __restrict__ Wk,
    const float* __restrict__ Wv, unsigned short* __restrict__ WF) {
  __shared__ __align__(16) unsigned short T[64][72];
  const int u = blockIdx.x >> 4, D0 = (blockIdx.x & 15) * 64;
  const int t = threadIdx.x;
  const float* src = (u < 16) ? (Wq + (size_t)u * 65536)
                   : (u < 20) ? (Wk + (size_t)(u - 16) * 65536)
                              : (Wv + (size_t)(u - 20) * 65536);
  const int e4 = (t & 15) * 4, dl = t >> 4;
  #pragma unroll
  for (int p = 0; p < 4; ++p) {
    const int d = p * 16 + dl;
    float4 v = *(const float4*)(src + (size_t)(D0 + d) * 64 + e4);
    T[e4 + 0][d] = f2bf(v.x); T[e4 + 1][d] = f2bf(v.y);
    T[e4 + 2][d] = f2bf(v.z); T[e4 + 3][d] = f2bf(v.w);
  }
  __syncthreads();
  const int j = t & 7;   // local d block of 8: d = j*8..j*8+7
  #pragma unroll
  for (int p = 0; p < 2; ++p) {
    const int e = p * 32 + (t >> 3);
    unsigned short* dst = WF + (size_t)u * 65536
        + (size_t)((e >> 4) * 32 + (D0 >> 5) + (j >> 2)) * 512
        + (e & 15) * 8 + (j & 3) * 128;
    *(s16x8*)dst = *(const s16x8*)&T[e][j * 8];
  }
}

// ---- k_project: AF x WF -> QF/KF/VF (all fragment-major) ---------------
// grid 384 = 8 strips(256 rows) x 2 b x 24 u, XCD-chunked (strip per XCD)
__global__ __launch_bounds__(256, 2) void k_project(
    const unsigned short* __restrict__ AF,
    const float* __restrict__ bq, const float* __restrict__ bk,
    const float* __restrict__ bv,
    const unsigned short* __restrict__ WF,
    unsigned short* __restrict__ QF,   // [b*16+h][128][2][512]
    unsigned short* __restrict__ KF,   // [b*4+g][128][2][512]
    unsigned short* __restrict__ VF) { // [b*4+g][4][64][512]
  const int i = blockIdx.x;
  const int strip = i & 7, rr = i >> 3;
  const int b = rr / 24, u = rr % 24;
  const int tid = threadIdx.x;
  const int w = tid >> 6, lane = tid & 63, lq = lane & 15, gq = lane >> 4;

  const unsigned short* AFp = AF
      + (size_t)((u < 16) ? 0 : (u < 20) ? 1 : 2) * 4194304
      + (size_t)b * 2097152;
  const float* bias = (u < 16) ? bq + u * 64
                    : (u < 20) ? bk + (u - 16) * 64 : bv + (u - 20) * 64;
  const unsigned short* WFp = WF + (size_t)u * 65536;
  const int sb0 = strip * 16 + w * 4;

  f32x4 acc[4][4] = {};
  #pragma unroll 2
  for (int dk = 0; dk < 32; ++dk) {
    s16x8 a[4], bf[4];
    #pragma unroll
    for (int rf = 0; rf < 4; ++rf)
      a[rf] = *(const s16x8*)(AFp + (size_t)((sb0 + rf) * 32 + dk) * 512 + lane * 8);
    #pragma unroll
    for (int n = 0; n < 4; ++n)
      bf[n] = *(const s16x8*)(WFp + (size_t)(n * 32 + dk) * 512 + lane * 8);
    #pragma unroll
    for (int rf = 0; rf < 4; ++rf)
      #pragma unroll
      for (int n = 0; n < 4; ++n)
        acc[rf][n] = __builtin_amdgcn_mfma_f32_16x16x32_bf16(a[rf], bf[n], acc[rf][n], 0, 0, 0);
  }

  float bvv[4];
  #pragma unroll
  for (int n = 0; n < 4; ++n) bvv[n] = bias[n * 16 + lq];

  unsigned short* dst = (u < 16) ? QF + (size_t)(b * 16 + u) * 131072
                      : (u < 20) ? KF + (size_t)(b * 4 + (u - 16)) * 131072
                                 : VF + (size_t)(b * 4 + (u - 20)) * 131072;
  #pragma unroll
  for (int rf = 0; rf < 4; ++rf)
    #pragma unroll
    for (int n = 0; n < 4; ++n)
      #pragma unroll
      for (int r = 0; r < 4; ++r) {
        const int s = strip * 256 + w * 64 + rf * 16 + gq * 4 + r;
        const int d = n * 16 + lq;
        const unsigned short hv = f2bf(acc[rf][n][r] + bvv[n]);
        if (u < 20)   // Q/K tile: row = s&15, k = d&31
          dst[(size_t)((s >> 4) * 2 + (d >> 5)) * 512
              + (s & 15) * 8 + ((d >> 3) & 3) * 128 + (d & 7)] = hv;
        else          // V tile: row = d&15 = lq, k = s&31
          dst[(size_t)(n * 64 + (s >> 5)) * 512
              + lq * 8 + ((s >> 3) & 3) * 128 + (s & 7)] = hv;
      }
}

// ---- k_attn: 1 wave/block, balanced pairs (j, 127-j), frag-major loads -
__global__ __launch_bounds__(64, 2) void k_attn(
    const unsigned short* __restrict__ QF, const unsigned short* __restrict__ KF,
    const unsigned short* __restrict__ VF, float* __restrict__ out) {
  __shared__ __align__(16) unsigned short P[16][72];
  const int lane = threadIdx.x, lq = lane & 15, gq = lane >> 4;
  const int bidx = blockIdx.x;                       // [0,1024)
  const int lid = (bidx & 7) * 128 + (bidx >> 3);    // XCD-chunked (j,h)
  const int pr = lid & 63, h = lid >> 6;
  const int b = blockIdx.y, g = h & 3;

  const unsigned short* QFp = QF + (size_t)(b * NH + h) * 131072;
  const unsigned short* KFp = KF + (size_t)(b * NG + g) * 131072;
  const unsigned short* VFp = VF + (size_t)(b * NG + g) * 131072;
  float* outp = out + (size_t)b * S_LEN * 1024 + h * 64;
  const float SC = 0.1803368801111204f;  // log2(e)/sqrt(64)

  auto process = [&](int j) {
    const int ntiles = (j >> 2) + 1;
    const s16x8 qf0 = *(const s16x8*)(QFp + (size_t)(j * 2 + 0) * 512 + lane * 8);
    const s16x8 qf1 = *(const s16x8*)(QFp + (size_t)(j * 2 + 1) * 512 + lane * 8);
    f32x4 z[4] = {};
    float m = -INFINITY, l = 0.f;

    auto loadK = [&](s16x8 (&A)[4], s16x8 (&B)[4], int t) {
      #pragma unroll
      for (int f = 0; f < 4; ++f) {
        const unsigned short* kp = KFp + (size_t)((t * 4 + f) * 2) * 512 + lane * 8;
        A[f] = *(const s16x8*)kp;
        B[f] = *(const s16x8*)(kp + 512);
      }
    };

    auto tile = [&](const s16x8 (&kA)[4], const s16x8 (&kB)[4], int t) {
      const int k0 = t * 64;
      s16x8 vb[4][2];
      #pragma unroll
      for (int n = 0; n < 4; ++n)
        #pragma unroll
        for (int ks = 0; ks < 2; ++ks)
          vb[n][ks] = *(const s16x8*)(VFp + (size_t)(n * 64 + t * 2 + ks) * 512 + lane * 8);
      // S^T = K·Q^T : lane col q = lq ; row k = k0 + f*16 + gq*4 + r
      f32x4 sv[4];
      __builtin_amdgcn_s_setprio(1);
      #pragma unroll
      for (int f = 0; f < 4; ++f) {
        f32x4 s = {};
        s = __builtin_amdgcn_mfma_f32_16x16x32_bf16(kA[f], qf0, s, 0, 0, 0);
        s = __builtin_amdgcn_mfma_f32_16x16x32_bf16(kB[f], qf1, s, 0, 0, 0);
        sv[f] = s;
      }
      __builtin_amdgcn_s_setprio(0);
      #pragma unroll
      for (int f = 0; f < 4; ++f)
        #pragma unroll
        for (int r = 0; r < 4; ++r) sv[f][r] *= SC;
      if (t == ntiles - 1) {
        const int qrow = j * 16 + lq;
        #pragma unroll
        for (int f = 0; f < 4; ++f)
          #pragma unroll
          for (int r = 0; r < 4; ++r)
            if (k0 + f * 16 + gq * 4 + r > qrow) sv[f][r] = -1e30f;
      }
      // per-q max (tree + 2 cross-group shuffles)
      float mf[4];
      #pragma unroll
      for (int f = 0; f < 4; ++f)
        mf[f] = fmaxf(fmaxf(sv[f][0], sv[f][1]), fmaxf(sv[f][2], sv[f][3]));
      float pm = fmaxf(fmaxf(mf[0], mf[1]), fmaxf(mf[2], mf[3]));
      pm = fmaxf(pm, __shfl_xor(pm, 16));
      pm = fmaxf(pm, __shfl_xor(pm, 32));
      // defer-max rescale (P bounded by 2^8)
      if (__any(pm - m > 8.f)) {
        const float mn = fmaxf(m, pm);
        const float sc = __builtin_amdgcn_exp2f(m - mn);
        m = mn; l *= sc;
        #pragma unroll
        for (int r = 0; r < 4; ++r) {
          float scr = __shfl(sc, gq * 4 + r, 64);
          z[0][r] *= scr; z[1][r] *= scr; z[2][r] *= scr; z[3][r] *= scr;
        }
      }
      // P = exp2(S - m) -> bf16 -> LDS layout swap
      float s0 = 0.f, s1 = 0.f;
      #pragma unroll
      for (int f = 0; f < 4; ++f) {
        float p0 = __builtin_amdgcn_exp2f(sv[f][0] - m);
        float p1 = __builtin_amdgcn_exp2f(sv[f][1] - m);
        float p2 = __builtin_amdgcn_exp2f(sv[f][2] - m);
        float p3 = __builtin_amdgcn_exp2f(sv[f][3] - m);
        s0 += p0 + p1; s1 += p2 + p3;
        *(uint2*)&P[lq][f * 16 + gq * 4] = make_uint2(cvtpk(p0, p1), cvtpk(p2, p3));
      }
      float ss = s0 + s1;
      ss += __shfl_xor(ss, 16);
      ss += __shfl_xor(ss, 32);
      l += ss;
      // PV
      s16x8 pa[2];
      #pragma unroll
      for (int ks = 0; ks < 2; ++ks)
        pa[ks] = *(const s16x8*)&P[lq][ks * 32 + gq * 8];
      __builtin_amdgcn_s_setprio(1);
      #pragma unroll
      for (int n = 0; n < 4; ++n)
        #pragma unroll
        for (int ks = 0; ks < 2; ++ks)
          z[n] = __builtin_amdgcn_mfma_f32_16x16x32_bf16(pa[ks], vb[n][ks], z[n], 0, 0, 0);
      __builtin_amdgcn_s_setprio(0);
    };

    // K double-buffer rotation
    s16x8 cA[4], cB[4], nA[4], nB[4];
    loadK(cA, cB, 0);
    int t = 0;
    while (true) {
      loadK(nA, nB, (t + 1 < ntiles) ? t + 1 : t);
      tile(cA, cB, t);
      if (++t >= ntiles) break;
      loadK(cA, cB, (t + 1 < ntiles) ? t + 1 : t);
      tile(nA, nB, t);
      if (++t >= ntiles) break;
    }

    // epilogue
    #pragma unroll
    for (int r = 0; r < 4; ++r) {
      float lr = __shfl(l, gq * 4 + r, 64);
      float inv = __builtin_amdgcn_rcpf(lr);
      float* op = outp + (size_t)(j * 16 + gq * 4 + r) * 1024;
      #pragma unroll
      for (int n = 0; n < 4; ++n) op[n * 16 + lq] = z[n][r] * inv;
    }
  };

  process(pr);
  process(127 - pr);
}

extern "C" void kernel_launch(void* const* d_in, const int* in_sizes, int n_in,
                              void* d_out, int out_size, void* d_ws, size_t ws_size,
                              hipStream_t stream) {
  const float* query = (const float*)d_in[0];
  const float* key   = (const float*)d_in[1];
  const float* value = (const float*)d_in[2];
  // d_in[3] = mask (causal tril; applied analytically)
  const float* Wq = (const float*)d_in[4];
  const float* bq = (const float*)d_in[5];
  const float* Wk = (const float*)d_in[6];
  const float* bk = (const float*)d_in[7];
  const float* Wv = (const float*)d_in[8];
  const float* bv = (const float*)d_in[9];
  float* out = (float*)d_out;

  unsigned short* AF = (unsigned short*)d_ws;          // 12,582,912 elems
  unsigned short* WF = AF + 12582912;                  //  1,572,864
  unsigned short* QF = WF + 1572864;                   //  4,194,304
  unsigned short* KF = QF + 4194304;                   //  1,048,576
  unsigned short* VF = KF + 1048576;                   //  1,048,576
  // total 20,447,232 elems = 40.9 MB

  hipLaunchKernelGGL(k_cast, dim3(2048, 3), dim3(256), 0, stream,
                     query, key, value, AF);
  hipLaunchKernelGGL(k_wtrans, dim3(384), dim3(256), 0, stream, Wq, Wk, Wv, WF);
  hipLaunchKernelGGL(k_project, dim3(384), dim3(256), 0, stream,
                     AF, bq, bk, bv, WF, QF, KF, VF);
  hipLaunchKernelGGL(k_attn, dim3(1024, 2), dim3(64), 0, stream, QF, KF, VF, out);
}